// Round 1
// baseline (4531.063 us; speedup 1.0000x reference)
//
#include <hip/hip_runtime.h>
#include <hip/hip_bf16.h>
#include <stdint.h>

typedef __hip_bfloat16 bf16;
typedef __attribute__((ext_vector_type(8))) short short8;
typedef __attribute__((ext_vector_type(4))) float f32x4;

#define NN 65536
#define DD 512
#define EE 1048576
#define GG 128
#define LL 512

static __device__ __forceinline__ void gld_lds16(const void* g, void* l) {
  __builtin_amdgcn_global_load_lds((const __attribute__((address_space(1))) uint32_t*)g,
                                   (__attribute__((address_space(3))) uint32_t*)l, 16, 0, 0);
}

// ---------------- prep: transpose/cast weights to bf16 ----------------
__global__ __launch_bounds__(256) void k_prep(
    const float* __restrict__ Wc, const float* __restrict__ Wf1, const float* __restrict__ Wf2,
    const float* __restrict__ Wih, const float* __restrict__ Whh,
    bf16* __restrict__ WcT, bf16* __restrict__ Wf1T, bf16* __restrict__ Wf2T,
    bf16* __restrict__ WihB, bf16* __restrict__ WhhB)
{
  const int i = blockIdx.x * 256 + threadIdx.x;
  if (i < 512 * 512) {
    const int k = i >> 9, n = i & 511;
    WcT [n * 512 + k] = __float2bfloat16(Wc [i]);
    Wf1T[n * 512 + k] = __float2bfloat16(Wf1[i]);
    Wf2T[n * 512 + k] = __float2bfloat16(Wf2[i]);
  }
  if (i < 1536 * 512) {
    WihB[i] = __float2bfloat16(Wih[i]);
    WhhB[i] = __float2bfloat16(Whh[i]);
  }
}

// ---------------- CSR build ----------------
__global__ __launch_bounds__(256) void k_deg(const int* __restrict__ dst, int* __restrict__ deg) {
  const int e = blockIdx.x * 256 + threadIdx.x;
  atomicAdd(&deg[dst[e]], 1);
}

__global__ __launch_bounds__(1024) void k_scan(const int* __restrict__ deg,
                                               int* __restrict__ roff, int* __restrict__ cursor) {
  __shared__ int sd[1024];
  __shared__ int carry;
  const int t = threadIdx.x;
  if (t == 0) carry = 0;
  __syncthreads();
  for (int c = 0; c < 64; ++c) {
    const int i = c * 1024 + t;
    const int v = deg[i];
    sd[t] = v;
    __syncthreads();
    for (int off = 1; off < 1024; off <<= 1) {
      int add = (t >= off) ? sd[t - off] : 0;
      __syncthreads();
      sd[t] += add;
      __syncthreads();
    }
    const int incl = sd[t];
    const int base = carry;
    roff[i]   = base + incl - v;
    cursor[i] = base + incl - v;
    __syncthreads();
    if (t == 1023) carry = base + incl;
    __syncthreads();
  }
  if (t == 0) roff[NN] = carry;
}

__global__ __launch_bounds__(256) void k_fill(const int* __restrict__ src, const int* __restrict__ dst,
                                              int* __restrict__ cursor, int* __restrict__ csr) {
  const int e = blockIdx.x * 256 + threadIdx.x;
  const int p = atomicAdd(&cursor[dst[e]], 1);
  csr[p] = src[e];
}

// ---------------- mean aggregation: one block per dst node ----------------
__global__ __launch_bounds__(128) void k_agg(
    const float* __restrict__ feats, const int* __restrict__ csr,
    const int* __restrict__ roff, bf16* __restrict__ agg)
{
  const int n = blockIdx.x, t = threadIdx.x;
  const int s0 = roff[n], s1 = roff[n + 1];
  float4 a = make_float4(0.f, 0.f, 0.f, 0.f);
  for (int i = s0; i < s1; ++i) {
    const int s = csr[i];
    const float4 v = *(const float4*)&feats[(long)s * 512 + t * 4];
    a.x += v.x; a.y += v.y; a.z += v.z; a.w += v.w;
  }
  const float sc = 1.f / fmaxf((float)(s1 - s0), 1.f);
  union { bf16 b[4]; ushort4 u; } pk;
  pk.b[0] = __float2bfloat16(a.x * sc);
  pk.b[1] = __float2bfloat16(a.y * sc);
  pk.b[2] = __float2bfloat16(a.z * sc);
  pk.b[3] = __float2bfloat16(a.w * sc);
  *(ushort4*)&agg[(long)n * 512 + t * 4] = pk.u;
}

// ---------------- bf16 GEMM: C[M,Ncols] = A[M,512] @ Bt[Ncols,512]^T + bias ----------------
// m97-style: 128x128 tile, BK=64, 4 waves (2x2), global_load_lds width-16.
template<bool GATHER, bool RELU, bool SCATTER>
__global__ __launch_bounds__(256) void k_gemm(
    const bf16* __restrict__ A, const bf16* __restrict__ Bt,
    const float* __restrict__ bias, const int* __restrict__ gidx,
    bf16* __restrict__ outb, float* __restrict__ outf, int Ncols)
{
  __shared__ bf16 lsA[128 * 64];
  __shared__ bf16 lsB[128 * 64];
  const int t = threadIdx.x;
  const int lane = t & 63, wid = t >> 6;
  const int wr = wid >> 1, wc = wid & 1;
  const int tm = blockIdx.y * 128, tn = blockIdx.x * 128;
  const int col8 = (t & 7) * 8;
  const int rsub = t >> 3;
  const int lc = lane & 15, lk = lane >> 4;

  long arow[4], brow[4];
#pragma unroll
  for (int i = 0; i < 4; ++i) {
    const int r = tm + i * 32 + rsub;
    int ar = r;
    if constexpr (GATHER) ar = gidx[r];
    arow[i] = (long)ar * 512;
    brow[i] = (long)(tn + i * 32 + rsub) * 512;
  }

  f32x4 acc[4][4];
#pragma unroll
  for (int a = 0; a < 4; ++a)
#pragma unroll
    for (int b = 0; b < 4; ++b) acc[a][b] = (f32x4){0.f, 0.f, 0.f, 0.f};

  for (int ks = 0; ks < 8; ++ks) {
    const int k0 = ks * 64;
#pragma unroll
    for (int i = 0; i < 4; ++i) {
      gld_lds16(A  + arow[i] + k0 + col8, &lsA[i * 2048 + t * 8]);
      gld_lds16(Bt + brow[i] + k0 + col8, &lsB[i * 2048 + t * 8]);
    }
    __syncthreads();
#pragma unroll
    for (int kk = 0; kk < 2; ++kk) {
      short8 af[4], bfr[4];
#pragma unroll
      for (int mi = 0; mi < 4; ++mi)
        af[mi] = *(const short8*)&lsA[(wr * 64 + mi * 16 + lc) * 64 + kk * 32 + lk * 8];
#pragma unroll
      for (int ni = 0; ni < 4; ++ni)
        bfr[ni] = *(const short8*)&lsB[(wc * 64 + ni * 16 + lc) * 64 + kk * 32 + lk * 8];
#pragma unroll
      for (int mi = 0; mi < 4; ++mi)
#pragma unroll
        for (int ni = 0; ni < 4; ++ni)
          acc[mi][ni] = __builtin_amdgcn_mfma_f32_16x16x32_bf16(af[mi], bfr[ni], acc[mi][ni], 0, 0, 0);
    }
    __syncthreads();
  }

  float bv[4];
#pragma unroll
  for (int ni = 0; ni < 4; ++ni) bv[ni] = bias[tn + wc * 64 + ni * 16 + lc];

#pragma unroll
  for (int mi = 0; mi < 4; ++mi) {
    const int r0 = tm + wr * 64 + mi * 16 + lk * 4;
#pragma unroll
    for (int j = 0; j < 4; ++j) {
      const int row = r0 + j;
      long orow;
      if constexpr (SCATTER) orow = (long)gidx[row] * 512;
      else                   orow = (long)row * Ncols;
#pragma unroll
      for (int ni = 0; ni < 4; ++ni) {
        float v = acc[mi][ni][j] + bv[ni];
        if constexpr (RELU) v = fmaxf(v, 0.f);
        const int c = tn + wc * 64 + ni * 16 + lc;
        if constexpr (SCATTER) outf[orow + c] = v;
        else                   outb[orow + c] = __float2bfloat16(v);
      }
    }
  }
}

// ---------------- GRU step: 64 blocks (jm in 0..1 groups-half, jc in 0..31 col-slice) ----------------
// gh = h @ Whh^T + bhh for 16 d-cols x 3 gates; elementwise update; h kept fp32 across steps.
__global__ __launch_bounds__(256) void k_gru(
    int l, const bf16* __restrict__ hb, const float* __restrict__ hf,
    bf16* __restrict__ hbn, float* __restrict__ hfn,
    const bf16* __restrict__ gi, const bf16* __restrict__ Whh,
    const float* __restrict__ bhh, bf16* __restrict__ ys)
{
  __shared__ bf16 lsW[48 * 520];  // rows padded to 520 elems -> conflict-free ds_read_b128
  __shared__ bf16 lsH[64 * 264];  // 64 group-rows x half-K (256) padded to 264
  const int t = threadIdx.x, lane = t & 63, w = t >> 6;
  const int jm = blockIdx.x >> 5, jc = blockIdx.x & 31;
  const int lc = lane & 15, lk = lane >> 4;

  // stage Whh slice: local rows 0..15 -> gate r, 16..31 -> z, 32..47 -> n (cols jc*16..+16)
#pragma unroll
  for (int it = 0; it < 12; ++it) {
    const int c = it * 256 + t;
    const int row = c >> 6, col = (c & 63) * 8;
    const int e = (row < 16) ? (jc * 16 + row)
                : (row < 32) ? (512 + jc * 16 + row - 16)
                             : (1024 + jc * 16 + row - 32);
    *(uint4*)&lsW[row * 520 + col] = *(const uint4*)&Whh[(long)e * 512 + col];
  }

  f32x4 acc[3];
#pragma unroll
  for (int ni = 0; ni < 3; ++ni) acc[ni] = (f32x4){0.f, 0.f, 0.f, 0.f};

  for (int half = 0; half < 2; ++half) {
    __syncthreads();  // first pass: covers W staging; second: protect lsH rewrite
#pragma unroll
    for (int it = 0; it < 8; ++it) {
      const int c = it * 256 + t;
      const int row = c >> 5, col = (c & 31) * 8;
      *(uint4*)&lsH[row * 264 + col] =
          *(const uint4*)&hb[(long)(jm * 64 + row) * 512 + half * 256 + col];
    }
    __syncthreads();
#pragma unroll
    for (int kk = 0; kk < 8; ++kk) {
      const short8 af = *(const short8*)&lsH[(w * 16 + lc) * 264 + kk * 32 + lk * 8];
#pragma unroll
      for (int ni = 0; ni < 3; ++ni) {
        const short8 bfr = *(const short8*)&lsW[(ni * 16 + lc) * 520 + half * 256 + kk * 32 + lk * 8];
        acc[ni] = __builtin_amdgcn_mfma_f32_16x16x32_bf16(af, bfr, acc[ni], 0, 0, 0);
      }
    }
  }

  const int d = jc * 16 + lc;
  const float bR = bhh[d], bZ = bhh[512 + d], bN = bhh[1024 + d];
#pragma unroll
  for (int j = 0; j < 4; ++j) {
    const int g = jm * 64 + w * 16 + lk * 4 + j;
    const long girow = ((long)g * 512 + l) * 1536;
    const float giR = __bfloat162float(gi[girow + d]);
    const float giZ = __bfloat162float(gi[girow + 512 + d]);
    const float giN = __bfloat162float(gi[girow + 1024 + d]);
    const float r = 1.f / (1.f + __expf(-(giR + acc[0][j] + bR)));
    const float z = 1.f / (1.f + __expf(-(giZ + acc[1][j] + bZ)));
    const float n = tanhf(giN + r * (acc[2][j] + bN));
    const float ho = hf[(long)g * 512 + d];
    const float hn = (1.f - z) * n + z * ho;
    hfn[(long)g * 512 + d] = hn;
    const bf16 hnb = __float2bfloat16(hn);
    hbn[(long)g * 512 + d] = hnb;
    ys[((long)g * 512 + l) * 512 + d] = hnb;
  }
}

// ---------------- launch ----------------
extern "C" void kernel_launch(void* const* d_in, const int* in_sizes, int n_in,
                              void* d_out, int out_size, void* d_ws, size_t ws_size,
                              hipStream_t stream)
{
  (void)in_sizes; (void)n_in; (void)out_size; (void)ws_size;
  const float* in_feats = (const float*)d_in[0];
  const int*   e_src    = (const int*)d_in[1];   (void)e_src;
  const int*   e_dst    = (const int*)d_in[2];
  const int*   seq      = (const int*)d_in[3];
  const float* W_conv   = (const float*)d_in[4];
  const float* b_conv   = (const float*)d_in[5];
  const float* W_ff1    = (const float*)d_in[6];
  const float* b_ff1    = (const float*)d_in[7];
  const float* W_ih     = (const float*)d_in[8];
  const float* W_hh     = (const float*)d_in[9];
  const float* b_ih     = (const float*)d_in[10];
  const float* b_hh     = (const float*)d_in[11];
  const float* W_ff2    = (const float*)d_in[12];
  const float* b_ff2    = (const float*)d_in[13];

  uint8_t* ws = (uint8_t*)d_ws;
  int*  deg    = (int*) (ws + 0);
  int*  cursor = (int*) (ws + (256u << 10));
  int*  roff   = (int*) (ws + (512u << 10));
  bf16* WcT    = (bf16*)(ws + 1048576u);
  bf16* Wf1T   = (bf16*)(ws + 1572864u);
  bf16* Wf2T   = (bf16*)(ws + 2097152u);
  bf16* WihB   = (bf16*)(ws + 2621440u);
  bf16* WhhB   = (bf16*)(ws + 4194304u);
  bf16* hbf0   = (bf16*)(ws + 5767168u);
  bf16* hbf1   = (bf16*)(ws + 5898240u);
  int*  csr    = (int*) (ws + 6291456u);
  float* hf0   = (float*)(ws + 10485760u);
  float* hf1   = (float*)(ws + 10747904u);
  bf16* med2   = (bf16*)(ws + 16777216u);    // region X: med2, later reused as ys
  bf16* ysb    = med2;
  bf16* gib    = (bf16*)(ws + 83886080u);    // 192MB region; agg/med1 live here pre-gi
  bf16* aggb   = (bf16*)(ws + 83886080u);
  bf16* med1   = (bf16*)(ws + 150994944u);

  bf16*  hbf[2] = {hbf0, hbf1};
  float* hfp[2] = {hf0, hf1};

  hipMemsetAsync(deg,    0, NN * 4,        stream);
  hipMemsetAsync(hbf[0], 0, GG * DD * 2,   stream);
  hipMemsetAsync(hfp[0], 0, GG * DD * 4,   stream);

  k_prep<<<3072, 256, 0, stream>>>(W_conv, W_ff1, W_ff2, W_ih, W_hh, WcT, Wf1T, Wf2T, WihB, WhhB);
  k_deg <<<EE / 256, 256, 0, stream>>>(e_dst, deg);
  k_scan<<<1, 1024, 0, stream>>>(deg, roff, cursor);
  k_fill<<<EE / 256, 256, 0, stream>>>((const int*)d_in[1], e_dst, cursor, csr);
  k_agg <<<NN, 128, 0, stream>>>(in_feats, csr, roff, aggb);

  dim3 g512(4, 512), g1536(12, 512);
  k_gemm<false, false, false><<<g512,  256, 0, stream>>>(aggb, WcT,  b_conv, nullptr, med1, nullptr, 512);
  k_gemm<false, true,  false><<<g512,  256, 0, stream>>>(med1, Wf1T, b_ff1,  nullptr, med2, nullptr, 512);
  k_gemm<true,  false, false><<<g1536, 256, 0, stream>>>(med2, WihB, b_ih,   seq,     gib,  nullptr, 1536);

  for (int l = 0; l < LL; ++l) {
    k_gru<<<64, 256, 0, stream>>>(l, hbf[l & 1], hfp[l & 1], hbf[(l + 1) & 1], hfp[(l + 1) & 1],
                                  gib, WhhB, b_hh, ysb);
  }

  k_gemm<false, false, true><<<g512, 256, 0, stream>>>(ysb, Wf2T, b_ff2, seq, nullptr, (float*)d_out, 512);
}